// Round 1
// baseline (1867.177 us; speedup 1.0000x reference)
//
#include <hip/hip_runtime.h>
#include <math.h>

// Problem constants: B=2,S=1024 -> T=2048 tokens; H=1024; I=2048; E=8; TOP_K=2
#define T_TOK 2048
#define H_DIM 1024
#define I_DIM 2048
#define NEXP  8

typedef _Float16 f16x8 __attribute__((ext_vector_type(8)));
typedef _Float16 f16x4 __attribute__((ext_vector_type(4)));
typedef float    f32x4 __attribute__((ext_vector_type(4)));

// ---------------------------------------------------------------------------
// async 16B global->LDS copy. LDS dest is WAVE-UNIFORM base + lane*16.
// ---------------------------------------------------------------------------
__device__ __forceinline__ void cp16(const void* g, void* l) {
  __builtin_amdgcn_global_load_lds(
      (const __attribute__((address_space(1))) void*)g,
      (__attribute__((address_space(3))) void*)l, 16, 0, 0);
}

// ---------------------------------------------------------------------------
// fp32 -> (f16 hi, f16 lo) split. hi+lo carries ~22 mantissa bits.
// n must be divisible by 1024 (grid*block*4).
// ---------------------------------------------------------------------------
__global__ __launch_bounds__(256) void split_kernel(
    const float* __restrict__ in, _Float16* __restrict__ hi,
    _Float16* __restrict__ lo, int n) {
  int i = (blockIdx.x * 256 + threadIdx.x) * 4;
  if (i >= n) return;
  float4 v = *(const float4*)(in + i);
  _Float16 h0 = (_Float16)v.x, h1 = (_Float16)v.y, h2 = (_Float16)v.z, h3 = (_Float16)v.w;
  _Float16 l0 = (_Float16)(v.x - (float)h0);
  _Float16 l1 = (_Float16)(v.y - (float)h1);
  _Float16 l2 = (_Float16)(v.z - (float)h2);
  _Float16 l3 = (_Float16)(v.w - (float)h3);
  f16x4 hv = {h0, h1, h2, h3};
  f16x4 lv = {l0, l1, l2, l3};
  *(f16x4*)(hi + i) = hv;
  *(f16x4*)(lo + i) = lv;
}

// ---------------------------------------------------------------------------
// Router: logits = x @ gw^T (8 experts), softmax, top-2, normalized weights.
// One wave per token.
// ---------------------------------------------------------------------------
__global__ __launch_bounds__(64) void router_kernel(
    const float* __restrict__ x, const float* __restrict__ gw,
    int* __restrict__ topIdx, float* __restrict__ topW) {
  int t = blockIdx.x;
  int lane = threadIdx.x;
  float p[NEXP];
#pragma unroll
  for (int e = 0; e < NEXP; ++e) p[e] = 0.f;
  const float* xr = x + (size_t)t * H_DIM;
  for (int h = lane; h < H_DIM; h += 64) {
    float xv = xr[h];
#pragma unroll
    for (int e = 0; e < NEXP; ++e) p[e] += xv * gw[e * H_DIM + h];
  }
#pragma unroll
  for (int e = 0; e < NEXP; ++e) {
    float v = p[e];
    for (int off = 32; off > 0; off >>= 1) v += __shfl_down(v, off);
    p[e] = v;
  }
  if (lane == 0) {
    float mx = p[0];
#pragma unroll
    for (int e = 1; e < NEXP; ++e) mx = fmaxf(mx, p[e]);
    float ex[NEXP], s = 0.f;
#pragma unroll
    for (int e = 0; e < NEXP; ++e) { ex[e] = expf(p[e] - mx); s += ex[e]; }
#pragma unroll
    for (int e = 0; e < NEXP; ++e) ex[e] /= s;
    int i0 = 0; float v0 = ex[0];
#pragma unroll
    for (int e = 1; e < NEXP; ++e) if (ex[e] > v0) { v0 = ex[e]; i0 = e; }
    int i1 = -1; float v1 = -1.f;
#pragma unroll
    for (int e = 0; e < NEXP; ++e) if (e != i0 && ex[e] > v1) { v1 = ex[e]; i1 = e; }
    float sum = fmaxf(v0 + v1, 1e-12f);
    topIdx[2 * t] = i0;  topIdx[2 * t + 1] = i1;
    topW[2 * t] = v0 / sum;  topW[2 * t + 1] = v1 / sum;
  }
}

// ---------------------------------------------------------------------------
// Split-precision GEMM-BT: C[M,N] = A[M,K] * B[N,K]^T, fp32 accumulate via
// 3-term f16 MFMA: Ahi*Bhi + Alo*Bhi + Ahi*Blo.
// 128x128 tile, BK=32, 256 threads (4 waves, 2x2, each 64x64 = 4x4 MFMA tiles).
// MODE 0: outF = silu(C)                        (gate pass -> tmp)
// MODE 1: inter = tmpIn * C; split->outHi/outLo (up pass -> inter)
// MODE 2: outF = C                              (down pass -> expert_out)
// ---------------------------------------------------------------------------
template <int MODE>
__global__ __launch_bounds__(256) void gemm_split(
    const _Float16* __restrict__ Ahi, const _Float16* __restrict__ Alo,
    const _Float16* __restrict__ Bhi, const _Float16* __restrict__ Blo,
    int K, int N, const float* __restrict__ tmpIn, float* __restrict__ outF,
    _Float16* __restrict__ outHi, _Float16* __restrict__ outLo) {
  __shared__ _Float16 lds[16384];  // 4 tiles of 128x32 f16 (8KB each) = 32KB

  const int tid = threadIdx.x;
  const int wave = tid >> 6, lane = tid & 63;
  const int rowA0 = blockIdx.y * 128;  // C-tile rows (A rows)
  const int colB0 = blockIdx.x * 128;  // C-tile cols (B rows)

  // staging: unit u covers tile row u>>2, f16 col (u&3)*8. units tid, tid+256.
  const int r0 = tid >> 2;
  const int c0 = (tid & 3) * 8;
  const int r1 = r0 + 64;
  const unsigned lb0 = (unsigned)wave * 1024u;          // byte base within tile
  const unsigned lb1 = 4096u + (unsigned)wave * 1024u;

  const int wm = wave >> 1, wn = wave & 1;
  const int fr = lane & 15;
  const int fk = (lane >> 4) * 8;

  f32x4 acc[4][4];
#pragma unroll
  for (int i = 0; i < 4; ++i)
#pragma unroll
    for (int j = 0; j < 4; ++j) acc[i][j] = (f32x4){0.f, 0.f, 0.f, 0.f};

  char* lb = (char*)lds;
  for (int k0 = 0; k0 < K; k0 += 32) {
    const size_t a0 = (size_t)(rowA0 + r0) * K + k0 + c0;
    const size_t a1 = (size_t)(rowA0 + r1) * K + k0 + c0;
    const size_t b0 = (size_t)(colB0 + r0) * K + k0 + c0;
    const size_t b1 = (size_t)(colB0 + r1) * K + k0 + c0;
    cp16(Ahi + a0, lb + 0 + lb0);
    cp16(Ahi + a1, lb + 0 + lb1);
    cp16(Alo + a0, lb + 8192 + lb0);
    cp16(Alo + a1, lb + 8192 + lb1);
    cp16(Bhi + b0, lb + 16384 + lb0);
    cp16(Bhi + b1, lb + 16384 + lb1);
    cp16(Blo + b0, lb + 24576 + lb0);
    cp16(Blo + b1, lb + 24576 + lb1);
    __syncthreads();  // compiler drains vmcnt before s_barrier

    f16x8 ah[4], al[4], bh[4], blv[4];
#pragma unroll
    for (int i = 0; i < 4; ++i) {
      const int ar = wm * 64 + i * 16 + fr;
      ah[i] = *(const f16x8*)&lds[ar * 32 + fk];
      al[i] = *(const f16x8*)&lds[4096 + ar * 32 + fk];
      const int br = wn * 64 + i * 16 + fr;
      bh[i] = *(const f16x8*)&lds[8192 + br * 32 + fk];
      blv[i] = *(const f16x8*)&lds[12288 + br * 32 + fk];
    }
#pragma unroll
    for (int i = 0; i < 4; ++i)
#pragma unroll
      for (int j = 0; j < 4; ++j) {
        acc[i][j] = __builtin_amdgcn_mfma_f32_16x16x32_f16(ah[i], bh[j], acc[i][j], 0, 0, 0);
        acc[i][j] = __builtin_amdgcn_mfma_f32_16x16x32_f16(al[i], bh[j], acc[i][j], 0, 0, 0);
        acc[i][j] = __builtin_amdgcn_mfma_f32_16x16x32_f16(ah[i], blv[j], acc[i][j], 0, 0, 0);
      }
    __syncthreads();  // protect LDS before next stage
  }

  // epilogue: C/D layout col=lane&15, row=(lane>>4)*4+reg (verified m89/m91)
  const int er = (lane >> 4) * 4;
  const int ec = lane & 15;
#pragma unroll
  for (int i = 0; i < 4; ++i)
#pragma unroll
    for (int j = 0; j < 4; ++j)
#pragma unroll
      for (int r = 0; r < 4; ++r) {
        const int row = rowA0 + wm * 64 + i * 16 + er + r;
        const int col = colB0 + wn * 64 + j * 16 + ec;
        const size_t idx = (size_t)row * N + col;
        float v = acc[i][j][r];
        if (MODE == 0) {
          outF[idx] = v / (1.f + expf(-v));  // silu
        } else if (MODE == 1) {
          float x = tmpIn[idx] * v;
          _Float16 h = (_Float16)x;
          _Float16 l = (_Float16)(x - (float)h);
          outHi[idx] = h;
          outLo[idx] = l;
        } else {
          outF[idx] = v;
        }
      }
}

// ---------------------------------------------------------------------------
// Gram: gram36[p] = sum_j eo[a][j]*eo[b][j] for pairs a<=b (36 of them).
// ---------------------------------------------------------------------------
__global__ __launch_bounds__(256) void gram_kernel(
    const float* __restrict__ eo, float* __restrict__ gram) {
  float s[36];
#pragma unroll
  for (int p = 0; p < 36; ++p) s[p] = 0.f;
  const size_t total = (size_t)T_TOK * H_DIM;  // 2097152 per expert
  const size_t stride = (size_t)gridDim.x * 256;
  for (size_t j = (size_t)blockIdx.x * 256 + threadIdx.x; j < total; j += stride) {
    float v[NEXP];
#pragma unroll
    for (int e = 0; e < NEXP; ++e) v[e] = eo[(size_t)e * total + j];
    int p = 0;
#pragma unroll
    for (int a = 0; a < NEXP; ++a)
#pragma unroll
      for (int b = a; b < NEXP; ++b) { s[p] += v[a] * v[b]; ++p; }
  }
#pragma unroll
  for (int p = 0; p < 36; ++p) {
    float v = s[p];
    for (int off = 32; off > 0; off >>= 1) v += __shfl_down(v, off);
    s[p] = v;
  }
  __shared__ float red[4][36];
  const int wave = threadIdx.x >> 6, lane = threadIdx.x & 63;
  if (lane == 0)
#pragma unroll
    for (int p = 0; p < 36; ++p) red[wave][p] = s[p];
  __syncthreads();
  if (threadIdx.x < 36) {
    float v = red[0][threadIdx.x] + red[1][threadIdx.x] + red[2][threadIdx.x] + red[3][threadIdx.x];
    atomicAdd(&gram[threadIdx.x], v);
  }
}

// ---------------------------------------------------------------------------
// Sim: 8x8 similarity from gram36. One wave; thread t -> (e1,e2).
// ---------------------------------------------------------------------------
__global__ __launch_bounds__(64) void sim_kernel(
    const float* __restrict__ gram, float* __restrict__ simOut) {
  const int t = threadIdx.x;
  const int e1 = t >> 3, e2 = t & 7;
  int a = e1 < e2 ? e1 : e2;
  int b = e1 < e2 ? e2 : e1;
  const float g = gram[a * 8 - a * (a - 1) / 2 + (b - a)];
  const float sq1 = gram[e1 * 8 - e1 * (e1 - 1) / 2];
  const float sq2 = gram[e2 * 8 - e2 * (e2 - 1) / 2];
  float d2 = fmaxf(sq1 + sq2 - 2.f * g, 0.f);
  float dist = (e1 == e2) ? 0.f : sqrtf(d2);
  float dmax = dist;
  for (int off = 32; off > 0; off >>= 1) dmax = fmaxf(dmax, __shfl_xor(dmax, off));
  float sim = 1.f - dist / fmaxf(dmax, 1e-12f);
  if (e1 == e2) sim = 1.f;
  simOut[t] = sim;
}

// ---------------------------------------------------------------------------
// Final: out[t] = w0*eo[i0][t] + w1*eo[i1][t]. One block per token.
// ---------------------------------------------------------------------------
__global__ __launch_bounds__(256) void final_kernel(
    const float* __restrict__ eo, const int* __restrict__ topIdx,
    const float* __restrict__ topW, float* __restrict__ out) {
  const int t = blockIdx.x;
  const int c = threadIdx.x * 4;
  const int i0 = topIdx[2 * t], i1 = topIdx[2 * t + 1];
  const float w0 = topW[2 * t], w1 = topW[2 * t + 1];
  const size_t per = (size_t)T_TOK * H_DIM;
  const float4 a = *(const float4*)&eo[(size_t)i0 * per + (size_t)t * H_DIM + c];
  const float4 b = *(const float4*)&eo[(size_t)i1 * per + (size_t)t * H_DIM + c];
  float4 r;
  r.x = w0 * a.x + w1 * b.x;
  r.y = w0 * a.y + w1 * b.y;
  r.z = w0 * a.z + w1 * b.z;
  r.w = w0 * a.w + w1 * b.w;
  *(float4*)&out[(size_t)t * H_DIM + c] = r;
}

// ---------------------------------------------------------------------------
// Workspace layout (bytes), total ~128 MB + 36 KB:
//  xHi 0(4M) xLo 4M | gupHi 8M(8M) gupLo 16M | dwnHi 24M(4M) dwnLo 28M
//  intHi 32M(8M) intLo 40M | tmp 48M(16M) | eo 64M(64M) | router/gram @128M
// ---------------------------------------------------------------------------
extern "C" void kernel_launch(void* const* d_in, const int* in_sizes, int n_in,
                              void* d_out, int out_size, void* d_ws, size_t ws_size,
                              hipStream_t stream) {
  (void)in_sizes; (void)n_in; (void)out_size; (void)ws_size;
  const float* x   = (const float*)d_in[0];  // (2,1024,1024)
  const float* gw  = (const float*)d_in[1];  // (8,1024)
  const float* gup = (const float*)d_in[2];  // (8,4096,1024)
  const float* dwn = (const float*)d_in[3];  // (8,1024,2048)
  float* out = (float*)d_out;                // final (2M) ++ sim (64)

  char* ws = (char*)d_ws;
  const size_t MB = 1u << 20;
  _Float16* xHi   = (_Float16*)(ws + 0 * MB);
  _Float16* xLo   = (_Float16*)(ws + 4 * MB);
  _Float16* gupHi = (_Float16*)(ws + 8 * MB);
  _Float16* gupLo = (_Float16*)(ws + 16 * MB);
  _Float16* dwnHi = (_Float16*)(ws + 24 * MB);
  _Float16* dwnLo = (_Float16*)(ws + 28 * MB);
  _Float16* intHi = (_Float16*)(ws + 32 * MB);
  _Float16* intLo = (_Float16*)(ws + 40 * MB);
  float*    tmpS  = (float*)(ws + 48 * MB);
  float*    eo    = (float*)(ws + 64 * MB);
  int*      topIdx = (int*)(ws + 128 * MB);
  float*    topW   = (float*)(ws + 128 * MB + 16384);
  float*    gram   = (float*)(ws + 128 * MB + 32768);

  // x split + router + gram zero
  split_kernel<<<2048, 256, 0, stream>>>(x, xHi, xLo, T_TOK * H_DIM);
  router_kernel<<<T_TOK, 64, 0, stream>>>(x, gw, topIdx, topW);
  hipMemsetAsync(gram, 0, 36 * sizeof(float), stream);

  for (int e = 0; e < NEXP; ++e) {
    const size_t gupOff = (size_t)e * 2 * I_DIM * H_DIM;  // 4096*1024
    const size_t dwnOff = (size_t)e * H_DIM * I_DIM;      // 1024*2048
    split_kernel<<<4096, 256, 0, stream>>>(gup + gupOff, gupHi, gupLo, 2 * I_DIM * H_DIM);
    split_kernel<<<2048, 256, 0, stream>>>(dwn + dwnOff, dwnHi, dwnLo, H_DIM * I_DIM);
    // gate half: tmp = silu(x @ gup[e][0:I]^T)   M=2048 N=2048 K=1024
    gemm_split<0><<<dim3(I_DIM / 128, T_TOK / 128), 256, 0, stream>>>(
        xHi, xLo, gupHi, gupLo, H_DIM, I_DIM, nullptr, tmpS, nullptr, nullptr);
    // up half: inter = tmp * (x @ gup[e][I:2I]^T) -> hi/lo
    gemm_split<1><<<dim3(I_DIM / 128, T_TOK / 128), 256, 0, stream>>>(
        xHi, xLo, gupHi + (size_t)I_DIM * H_DIM, gupLo + (size_t)I_DIM * H_DIM,
        H_DIM, I_DIM, tmpS, nullptr, intHi, intLo);
    // down: eo[e] = inter @ dwn[e]^T   M=2048 N=1024 K=2048
    gemm_split<2><<<dim3(H_DIM / 128, T_TOK / 128), 256, 0, stream>>>(
        intHi, intLo, dwnHi, dwnLo, I_DIM, H_DIM, nullptr,
        eo + (size_t)e * T_TOK * H_DIM, nullptr, nullptr);
  }

  gram_kernel<<<2048, 256, 0, stream>>>(eo, gram);
  sim_kernel<<<1, 64, 0, stream>>>(gram, out + (size_t)T_TOK * H_DIM);
  final_kernel<<<T_TOK, 256, 0, stream>>>(eo, topIdx, topW, out);
}

// Round 2
// 681.489 us; speedup vs baseline: 2.7398x; 2.7398x over previous
//
#include <hip/hip_runtime.h>
#include <math.h>

// Problem constants: B=2,S=1024 -> T=2048 tokens; H=1024; I=2048; E=8; TOP_K=2
#define T_TOK 2048
#define H_DIM 1024
#define I_DIM 2048
#define NEXP  8

typedef _Float16 f16x8 __attribute__((ext_vector_type(8)));
typedef _Float16 f16x4 __attribute__((ext_vector_type(4)));
typedef float    f32x4 __attribute__((ext_vector_type(4)));

// ---------------------------------------------------------------------------
// async 16B global->LDS copy. LDS dest = WAVE-UNIFORM base + lane*16.
// ---------------------------------------------------------------------------
__device__ __forceinline__ void cp16(const void* g, void* l) {
  __builtin_amdgcn_global_load_lds(
      (const __attribute__((address_space(1))) void*)g,
      (__attribute__((address_space(3))) void*)l, 16, 0, 0);
}

// ---------------------------------------------------------------------------
// load 8 consecutive fp32, split to f16 hi + lo, ds_write_b128 each.
// ---------------------------------------------------------------------------
__device__ __forceinline__ void stage8(const float* __restrict__ src,
                                       _Float16* dstHi, _Float16* dstLo) {
  float4 f0 = ((const float4*)src)[0];
  float4 f1 = ((const float4*)src)[1];
  float v[8] = {f0.x, f0.y, f0.z, f0.w, f1.x, f1.y, f1.z, f1.w};
  f16x8 h, l;
#pragma unroll
  for (int i = 0; i < 8; ++i) {
    _Float16 hh = (_Float16)v[i];
    h[i] = hh;
    l[i] = (_Float16)(v[i] - (float)hh);
  }
  *(f16x8*)dstHi = h;
  *(f16x8*)dstLo = l;
}

// ---------------------------------------------------------------------------
// fp32 -> f16 (hi only) for x. n divisible by 1024.
// ---------------------------------------------------------------------------
__global__ __launch_bounds__(256) void split_x_kernel(
    const float* __restrict__ in, _Float16* __restrict__ hi, int n) {
  int i = (blockIdx.x * 256 + threadIdx.x) * 4;
  if (i >= n) return;
  float4 v = *(const float4*)(in + i);
  f16x4 hv = {(_Float16)v.x, (_Float16)v.y, (_Float16)v.z, (_Float16)v.w};
  *(f16x4*)(hi + i) = hv;
}

// ---------------------------------------------------------------------------
// Router: logits = x @ gw^T, softmax, top-2, normalized weights. 1 wave/token.
// ---------------------------------------------------------------------------
__global__ __launch_bounds__(64) void router_kernel(
    const float* __restrict__ x, const float* __restrict__ gw,
    int* __restrict__ topIdx, float* __restrict__ topW) {
  int t = blockIdx.x;
  int lane = threadIdx.x;
  float p[NEXP];
#pragma unroll
  for (int e = 0; e < NEXP; ++e) p[e] = 0.f;
  const float* xr = x + (size_t)t * H_DIM;
  for (int h = lane; h < H_DIM; h += 64) {
    float xv = xr[h];
#pragma unroll
    for (int e = 0; e < NEXP; ++e) p[e] += xv * gw[e * H_DIM + h];
  }
#pragma unroll
  for (int e = 0; e < NEXP; ++e) {
    float v = p[e];
    for (int off = 32; off > 0; off >>= 1) v += __shfl_down(v, off);
    p[e] = v;
  }
  if (lane == 0) {
    float mx = p[0];
#pragma unroll
    for (int e = 1; e < NEXP; ++e) mx = fmaxf(mx, p[e]);
    float ex[NEXP], s = 0.f;
#pragma unroll
    for (int e = 0; e < NEXP; ++e) { ex[e] = expf(p[e] - mx); s += ex[e]; }
#pragma unroll
    for (int e = 0; e < NEXP; ++e) ex[e] /= s;
    int i0 = 0; float v0 = ex[0];
#pragma unroll
    for (int e = 1; e < NEXP; ++e) if (ex[e] > v0) { v0 = ex[e]; i0 = e; }
    int i1 = -1; float v1 = -1.f;
#pragma unroll
    for (int e = 0; e < NEXP; ++e) if (e != i0 && ex[e] > v1) { v1 = ex[e]; i1 = e; }
    float sum = fmaxf(v0 + v1, 1e-12f);
    topIdx[2 * t] = i0;  topIdx[2 * t + 1] = i1;
    topW[2 * t] = v0 / sum;  topW[2 * t + 1] = v1 / sum;
  }
}

// ---------------------------------------------------------------------------
// Fused gate+up GEMM, all experts batched via gridDim.z.
// inter[e][t][i] = silu(x@Wg^T) * (x@Wu^T), stored f16.
// C = A[M,K] * B[N,K]^T with M=T, N=I, K=H. 128x128 tile, BK=32, 4 waves 2x2.
// Terms per output: Ahi*Bhi + Ahi*Blo (weights on-the-fly split fp32->hi/lo).
// XOR swizzle: LDS slot s of row r holds global k-chunk s ^ ((r^(r>>2))&3).
// ---------------------------------------------------------------------------
__global__ __launch_bounds__(256, 2) void gemm_gateup(
    const _Float16* __restrict__ xHi, const float* __restrict__ gup,
    _Float16* __restrict__ intHi) {
  // halves offsets: aHi 0, bgHi 4096, bgLo 8192, buHi 12288, buLo 16384
  __shared__ _Float16 lds[20480];  // 40 KB

  const int tid = threadIdx.x;
  const int wave = tid >> 6, lane = tid & 63;
  const int rowA0 = blockIdx.x * 128;  // M tile (x fastest -> consecutive blocks share B)
  const int colB0 = blockIdx.y * 128;  // N tile within I
  const int e = blockIdx.z;

  // staging coords: thread t -> row r0 (and r0+64), LDS chunk slot s0
  const int r0 = tid >> 2;
  const int s0 = tid & 3;
  const int swr = (r0 ^ (r0 >> 2)) & 3;   // same for r0+64
  const int g0 = s0 ^ swr;                // global k-chunk loaded

  const int wm = wave >> 1, wn = wave & 1;
  const int fr = lane & 15;
  const int quad = lane >> 4;
  const int swf = (fr ^ (fr >> 2)) & 3;
  const int fk = (quad ^ swf) * 8;        // swizzled chunk offset (halves)

  f32x4 accG[4][4], accU[4][4];
#pragma unroll
  for (int i = 0; i < 4; ++i)
#pragma unroll
    for (int j = 0; j < 4; ++j) {
      accG[i][j] = (f32x4){0.f, 0.f, 0.f, 0.f};
      accU[i][j] = (f32x4){0.f, 0.f, 0.f, 0.f};
    }

  const float* gupG = gup + ((size_t)e * 2 * I_DIM + colB0) * H_DIM;
  const float* gupU = gup + ((size_t)e * 2 * I_DIM + I_DIM + colB0) * H_DIM;
  char* ldsB = (char*)lds;

  for (int k0 = 0; k0 < H_DIM; k0 += 32) {
    const int kcol = k0 + g0 * 8;
    // A (x hi) via async direct-to-LDS
    cp16(xHi + (size_t)(rowA0 + r0) * H_DIM + kcol, ldsB + wave * 1024u);
    cp16(xHi + (size_t)(rowA0 + r0 + 64) * H_DIM + kcol, ldsB + 4096u + wave * 1024u);
    // B gate/up: fp32 load -> hi/lo split -> LDS (conflict-free linear writes)
    const size_t bro0 = (size_t)r0 * H_DIM + kcol;
    const size_t bro1 = bro0 + (size_t)64 * H_DIM;
    const int lo0 = r0 * 32 + s0 * 8;
    const int lo1 = lo0 + 64 * 32;
    stage8(gupG + bro0, &lds[4096 + lo0], &lds[8192 + lo0]);
    stage8(gupG + bro1, &lds[4096 + lo1], &lds[8192 + lo1]);
    stage8(gupU + bro0, &lds[12288 + lo0], &lds[16384 + lo0]);
    stage8(gupU + bro1, &lds[12288 + lo1], &lds[16384 + lo1]);
    __syncthreads();

    f16x8 ah[4];
#pragma unroll
    for (int i = 0; i < 4; ++i)
      ah[i] = *(const f16x8*)&lds[(wm * 64 + i * 16 + fr) * 32 + fk];
#pragma unroll
    for (int j = 0; j < 4; ++j) {
      const int boff = (wn * 64 + j * 16 + fr) * 32 + fk;
      f16x8 bh = *(const f16x8*)&lds[4096 + boff];
      f16x8 bl = *(const f16x8*)&lds[8192 + boff];
#pragma unroll
      for (int i = 0; i < 4; ++i) {
        accG[i][j] = __builtin_amdgcn_mfma_f32_16x16x32_f16(ah[i], bh, accG[i][j], 0, 0, 0);
        accG[i][j] = __builtin_amdgcn_mfma_f32_16x16x32_f16(ah[i], bl, accG[i][j], 0, 0, 0);
      }
      f16x8 uh = *(const f16x8*)&lds[12288 + boff];
      f16x8 ul = *(const f16x8*)&lds[16384 + boff];
#pragma unroll
      for (int i = 0; i < 4; ++i) {
        accU[i][j] = __builtin_amdgcn_mfma_f32_16x16x32_f16(ah[i], uh, accU[i][j], 0, 0, 0);
        accU[i][j] = __builtin_amdgcn_mfma_f32_16x16x32_f16(ah[i], ul, accU[i][j], 0, 0, 0);
      }
    }
    __syncthreads();
  }

  // epilogue: C/D layout col=lane&15, row=quad*4+reg. inter = silu(g)*u -> f16
  const int er = quad * 4;
  const int ec = lane & 15;
#pragma unroll
  for (int i = 0; i < 4; ++i)
#pragma unroll
    for (int j = 0; j < 4; ++j) {
      const int row = rowA0 + wm * 64 + i * 16 + er;
      const int col = colB0 + wn * 64 + j * 16 + ec;
#pragma unroll
      for (int r = 0; r < 4; ++r) {
        float g = accG[i][j][r], u = accU[i][j][r];
        float val = g / (1.f + __expf(-g)) * u;
        intHi[((size_t)e * T_TOK + row + r) * I_DIM + col] = (_Float16)val;
      }
    }
}

// ---------------------------------------------------------------------------
// Down GEMM, all experts batched. eo[e][t][h] (f16) = inter @ dwn[e]^T.
// M=T, N=H, K=I. Terms: Ahi*Bhi + Ahi*Blo.
// ---------------------------------------------------------------------------
__global__ __launch_bounds__(256, 2) void gemm_down(
    const _Float16* __restrict__ intHi, const float* __restrict__ dwn,
    _Float16* __restrict__ eo) {
  // halves offsets: aHi 0, bHi 4096, bLo 8192
  __shared__ _Float16 lds[12288];  // 24 KB

  const int tid = threadIdx.x;
  const int wave = tid >> 6, lane = tid & 63;
  const int rowA0 = blockIdx.x * 128;
  const int colB0 = blockIdx.y * 128;
  const int e = blockIdx.z;

  const int r0 = tid >> 2;
  const int s0 = tid & 3;
  const int swr = (r0 ^ (r0 >> 2)) & 3;
  const int g0 = s0 ^ swr;

  const int wm = wave >> 1, wn = wave & 1;
  const int fr = lane & 15;
  const int quad = lane >> 4;
  const int swf = (fr ^ (fr >> 2)) & 3;
  const int fk = (quad ^ swf) * 8;

  f32x4 acc[4][4];
#pragma unroll
  for (int i = 0; i < 4; ++i)
#pragma unroll
    for (int j = 0; j < 4; ++j) acc[i][j] = (f32x4){0.f, 0.f, 0.f, 0.f};

  const _Float16* aBase = intHi + (size_t)e * T_TOK * I_DIM;
  const float* bBase = dwn + ((size_t)e * H_DIM + colB0) * I_DIM;
  char* ldsB = (char*)lds;

  for (int k0 = 0; k0 < I_DIM; k0 += 32) {
    const int kcol = k0 + g0 * 8;
    cp16(aBase + (size_t)(rowA0 + r0) * I_DIM + kcol, ldsB + wave * 1024u);
    cp16(aBase + (size_t)(rowA0 + r0 + 64) * I_DIM + kcol, ldsB + 4096u + wave * 1024u);
    const size_t bro0 = (size_t)r0 * I_DIM + kcol;
    const size_t bro1 = bro0 + (size_t)64 * I_DIM;
    const int lo0 = r0 * 32 + s0 * 8;
    const int lo1 = lo0 + 64 * 32;
    stage8(bBase + bro0, &lds[4096 + lo0], &lds[8192 + lo0]);
    stage8(bBase + bro1, &lds[4096 + lo1], &lds[8192 + lo1]);
    __syncthreads();

    f16x8 ah[4];
#pragma unroll
    for (int i = 0; i < 4; ++i)
      ah[i] = *(const f16x8*)&lds[(wm * 64 + i * 16 + fr) * 32 + fk];
#pragma unroll
    for (int j = 0; j < 4; ++j) {
      const int boff = (wn * 64 + j * 16 + fr) * 32 + fk;
      f16x8 bh = *(const f16x8*)&lds[4096 + boff];
      f16x8 bl = *(const f16x8*)&lds[8192 + boff];
#pragma unroll
      for (int i = 0; i < 4; ++i) {
        acc[i][j] = __builtin_amdgcn_mfma_f32_16x16x32_f16(ah[i], bh, acc[i][j], 0, 0, 0);
        acc[i][j] = __builtin_amdgcn_mfma_f32_16x16x32_f16(ah[i], bl, acc[i][j], 0, 0, 0);
      }
    }
    __syncthreads();
  }

  const int er = quad * 4;
  const int ec = lane & 15;
#pragma unroll
  for (int i = 0; i < 4; ++i)
#pragma unroll
    for (int j = 0; j < 4; ++j) {
      const int row = rowA0 + wm * 64 + i * 16 + er;
      const int col = colB0 + wn * 64 + j * 16 + ec;
#pragma unroll
      for (int r = 0; r < 4; ++r)
        eo[((size_t)e * T_TOK + row + r) * H_DIM + col] = (_Float16)acc[i][j][r];
    }
}

// ---------------------------------------------------------------------------
// Gram: gram36[p] = sum_j eo[a][j]*eo[b][j] for pairs a<=b.
// ---------------------------------------------------------------------------
__global__ __launch_bounds__(256) void gram_kernel(
    const _Float16* __restrict__ eo, float* __restrict__ gram) {
  float s[36];
#pragma unroll
  for (int p = 0; p < 36; ++p) s[p] = 0.f;
  const size_t total = (size_t)T_TOK * H_DIM;
  const size_t stride = (size_t)gridDim.x * 256;
  for (size_t j = (size_t)blockIdx.x * 256 + threadIdx.x; j < total; j += stride) {
    float v[NEXP];
#pragma unroll
    for (int e = 0; e < NEXP; ++e) v[e] = (float)eo[(size_t)e * total + j];
    int p = 0;
#pragma unroll
    for (int a = 0; a < NEXP; ++a)
#pragma unroll
      for (int b = a; b < NEXP; ++b) { s[p] += v[a] * v[b]; ++p; }
  }
#pragma unroll
  for (int p = 0; p < 36; ++p) {
    float v = s[p];
    for (int off = 32; off > 0; off >>= 1) v += __shfl_down(v, off);
    s[p] = v;
  }
  __shared__ float red[4][36];
  const int wave = threadIdx.x >> 6, lane = threadIdx.x & 63;
  if (lane == 0)
#pragma unroll
    for (int p = 0; p < 36; ++p) red[wave][p] = s[p];
  __syncthreads();
  if (threadIdx.x < 36) {
    float v = red[0][threadIdx.x] + red[1][threadIdx.x] + red[2][threadIdx.x] + red[3][threadIdx.x];
    atomicAdd(&gram[threadIdx.x], v);
  }
}

// ---------------------------------------------------------------------------
// Sim: 8x8 similarity from gram36.
// ---------------------------------------------------------------------------
__global__ __launch_bounds__(64) void sim_kernel(
    const float* __restrict__ gram, float* __restrict__ simOut) {
  const int t = threadIdx.x;
  const int e1 = t >> 3, e2 = t & 7;
  int a = e1 < e2 ? e1 : e2;
  int b = e1 < e2 ? e2 : e1;
  const float g = gram[a * 8 - a * (a - 1) / 2 + (b - a)];
  const float sq1 = gram[e1 * 8 - e1 * (e1 - 1) / 2];
  const float sq2 = gram[e2 * 8 - e2 * (e2 - 1) / 2];
  float d2 = fmaxf(sq1 + sq2 - 2.f * g, 0.f);
  float dist = (e1 == e2) ? 0.f : sqrtf(d2);
  float dmax = dist;
  for (int off = 32; off > 0; off >>= 1) dmax = fmaxf(dmax, __shfl_xor(dmax, off));
  float sim = 1.f - dist / fmaxf(dmax, 1e-12f);
  if (e1 == e2) sim = 1.f;
  simOut[t] = sim;
}

// ---------------------------------------------------------------------------
// Final: out[t] = w0*eo[i0][t] + w1*eo[i1][t]. One block per token.
// ---------------------------------------------------------------------------
__global__ __launch_bounds__(256) void final_kernel(
    const _Float16* __restrict__ eo, const int* __restrict__ topIdx,
    const float* __restrict__ topW, float* __restrict__ out) {
  const int t = blockIdx.x;
  const int c = threadIdx.x * 4;
  const int i0 = topIdx[2 * t], i1 = topIdx[2 * t + 1];
  const float w0 = topW[2 * t], w1 = topW[2 * t + 1];
  const size_t per = (size_t)T_TOK * H_DIM;
  f16x4 a = *(const f16x4*)&eo[(size_t)i0 * per + (size_t)t * H_DIM + c];
  f16x4 b = *(const f16x4*)&eo[(size_t)i1 * per + (size_t)t * H_DIM + c];
  float4 r;
  r.x = w0 * (float)a[0] + w1 * (float)b[0];
  r.y = w0 * (float)a[1] + w1 * (float)b[1];
  r.z = w0 * (float)a[2] + w1 * (float)b[2];
  r.w = w0 * (float)a[3] + w1 * (float)b[3];
  *(float4*)&out[(size_t)t * H_DIM + c] = r;
}

// ---------------------------------------------------------------------------
// Workspace layout (bytes), total ~101 MiB (known-safe: round-1 used 128 MiB):
//  xHi @0 (4 MiB) | intHi @4 MiB (64 MiB) | eo f16 @68 MiB (32 MiB)
//  topIdx @100 MiB | topW @100 MiB+16K | gram @100 MiB+32K
// ---------------------------------------------------------------------------
extern "C" void kernel_launch(void* const* d_in, const int* in_sizes, int n_in,
                              void* d_out, int out_size, void* d_ws, size_t ws_size,
                              hipStream_t stream) {
  (void)in_sizes; (void)n_in; (void)out_size; (void)ws_size;
  const float* x   = (const float*)d_in[0];  // (2,1024,1024)
  const float* gw  = (const float*)d_in[1];  // (8,1024)
  const float* gup = (const float*)d_in[2];  // (8,4096,1024)
  const float* dwn = (const float*)d_in[3];  // (8,1024,2048)
  float* out = (float*)d_out;                // final (2M) ++ sim (64)

  char* ws = (char*)d_ws;
  const size_t MB = 1u << 20;
  _Float16* xHi    = (_Float16*)(ws + 0 * MB);
  _Float16* intHi  = (_Float16*)(ws + 4 * MB);
  _Float16* eo     = (_Float16*)(ws + 68 * MB);
  int*      topIdx = (int*)(ws + 100 * MB);
  float*    topW   = (float*)(ws + 100 * MB + 16384);
  float*    gram   = (float*)(ws + 100 * MB + 32768);

  split_x_kernel<<<2048, 256, 0, stream>>>(x, xHi, T_TOK * H_DIM);
  router_kernel<<<T_TOK, 64, 0, stream>>>(x, gw, topIdx, topW);
  hipMemsetAsync(gram, 0, 36 * sizeof(float), stream);

  // gate+up fused, all experts: grid x=M tiles (fastest, shares B), y=N, z=E
  gemm_gateup<<<dim3(T_TOK / 128, I_DIM / 128, NEXP), 256, 0, stream>>>(
      xHi, gup, intHi);
  // down, all experts
  gemm_down<<<dim3(T_TOK / 128, H_DIM / 128, NEXP), 256, 0, stream>>>(
      intHi, dwn, eo);

  gram_kernel<<<2048, 256, 0, stream>>>(eo, gram);
  sim_kernel<<<1, 64, 0, stream>>>(gram, out + (size_t)T_TOK * H_DIM);
  final_kernel<<<T_TOK, 256, 0, stream>>>(eo, topIdx, topW, out);
}